// Round 1
// baseline (301.311 us; speedup 1.0000x reference)
//
#include <hip/hip_runtime.h>

#define BATCH 4
#define HH 56
#define WW 56
#define CC 128
#define NHD 4
#define HD 32
#define KS 7
#define NB 3
#define HWSZ (HH * WW)        // 3136
#define RPBW 13
#define QKV_ELE ((size_t)BATCH * NHD * HWSZ * HD)   // 1,605,632 floats per tensor

// ---------------- Kernel 1: QKV GEMM ----------------
// x [12544,128] @ w_qkv[128,384] + b_qkv -> q/k/v each in [B,NH,H,W,HD] layout.
// q is pre-scaled by hd^-0.5. Block = 384 threads (col = tid), 32-row tile.
// x tile staged in LDS; reads are wave-uniform (broadcast, conflict-free).
__global__ __launch_bounds__(384) void qkv_gemm(
    const float* __restrict__ x, const float* __restrict__ w,
    const float* __restrict__ bias,
    float* __restrict__ qb, float* __restrict__ kb, float* __restrict__ vb)
{
    __shared__ float4 xs[1024];   // 32 rows x 128 cols (16 KB)
    const int tid = threadIdx.x;
    const int m0 = blockIdx.x * 32;

    const float4* xg = (const float4*)(x + (size_t)m0 * CC);
    for (int idx = tid; idx < 1024; idx += 384) xs[idx] = xg[idx];
    __syncthreads();

    const int col = tid;          // 0..383
    float acc[32];
    const float bv = bias[col];
    #pragma unroll
    for (int r = 0; r < 32; ++r) acc[r] = bv;

    for (int kc = 0; kc < 32; ++kc) {
        const float w0 = w[(kc * 4 + 0) * 384 + col];
        const float w1 = w[(kc * 4 + 1) * 384 + col];
        const float w2 = w[(kc * 4 + 2) * 384 + col];
        const float w3 = w[(kc * 4 + 3) * 384 + col];
        #pragma unroll
        for (int r = 0; r < 32; ++r) {
            const float4 xv = xs[r * 32 + kc];   // uniform across wave -> broadcast
            acc[r] += xv.x * w0 + xv.y * w1 + xv.z * w2 + xv.w * w3;
        }
    }

    const int t    = col >> 7;        // 0=q 1=k 2=v
    const int rem  = col & 127;
    const int head = rem >> 5;
    const int d    = rem & 31;
    const float scale = (t == 0) ? 0.17677669529663687f : 1.0f;  // 32^-0.5
    float* dst = (t == 0) ? qb : (t == 1) ? kb : vb;

    const int b   = m0 / HWSZ;        // 32 | 3136 so tile never crosses b
    const int ij0 = m0 - b * HWSZ;
    float* dsth = dst + (size_t)(b * NHD + head) * HWSZ * HD + d;
    #pragma unroll
    for (int r = 0; r < 32; ++r) {
        dsth[(size_t)(ij0 + r) * HD] = acc[r] * scale;
    }
}

// ---------------- Kernel 2: neighborhood attention ----------------
// grid = (49 tiles, 2 head-pairs, B). Block = 128 threads = 2 heads x (8x8 queries).
// LDS holds the 14x14 key halo for both heads; buffer reused for V (barriered).
__global__ __launch_bounds__(128) void natten_attn(
    const float* __restrict__ qb, const float* __restrict__ kb,
    const float* __restrict__ vb, const float* __restrict__ rpb,
    float* __restrict__ ob)
{
    __shared__ float4 kv[2][8][196];   // [head2][c][pos] = 50176 B

    const int tid  = threadIdx.x;
    const int h2   = tid >> 6;         // wave-uniform
    const int lane = tid & 63;
    const int qi_l = lane >> 3;
    const int qj_l = lane & 7;
    const int ti = blockIdx.x / 7;
    const int tj = blockIdx.x % 7;
    const int hp = blockIdx.y;
    const int b  = blockIdx.z;
    const int head = hp * 2 + h2;
    const int qi = ti * 8 + qi_l;
    const int qj = tj * 8 + qj_l;
    // staged window origin: 14x14 rows/cols guaranteed in-bounds and covering
    const int R0 = min(max(ti * 8 - NB, 0), HH - 14);
    const int C0 = min(max(tj * 8 - NB, 0), WW - 14);

    const size_t base0 = (size_t)(b * NHD + hp * 2) * HWSZ;

    // ---- stage K (2 heads x 196 pos x 8 float4) ----
    for (int idx = tid; idx < 2 * 196 * 8; idx += 128) {
        const int h   = idx / 1568;
        const int rem = idx - h * 1568;
        const int pos = rem >> 3;
        const int c   = rem & 7;
        const int ri  = pos / 14;
        const int rj  = pos - ri * 14;
        const float4* src = (const float4*)(kb +
            (base0 + (size_t)h * HWSZ + (R0 + ri) * WW + (C0 + rj)) * HD) + c;
        kv[h][c][pos] = *src;
    }

    // load q fragment (already scaled)
    float4 qv[8];
    const float* qptr = qb + ((size_t)(b * NHD + head) * HWSZ + qi * WW + qj) * HD;
    #pragma unroll
    for (int c = 0; c < 8; ++c) qv[c] = ((const float4*)qptr)[c];

    const int si  = min(max(qi - NB, 0), HH - KS);
    const int sj  = min(max(qj - NB, 0), WW - KS);
    const int ri0 = si - R0;
    const int rj0 = sj - C0;
    const int oi  = si - qi + (KS - 1);
    const int oj  = sj - qj + (KS - 1);
    const float* rpbh = rpb + head * (RPBW * RPBW);

    __syncthreads();   // K staged

    float s[49];
    #pragma unroll
    for (int pi = 0; pi < 7; ++pi) {
        #pragma unroll
        for (int pj = 0; pj < 7; ++pj) {
            const int pos = (ri0 + pi) * 14 + (rj0 + pj);
            float d = 0.f;
            #pragma unroll
            for (int c = 0; c < 8; ++c) {
                const float4 kk = kv[h2][c][pos];
                d += qv[c].x * kk.x + qv[c].y * kk.y + qv[c].z * kk.z + qv[c].w * kk.w;
            }
            s[pi * 7 + pj] = d + rpbh[(oi + pi) * RPBW + (oj + pj)];
        }
    }

    __syncthreads();   // everyone done reading K

    // ---- stage V into the same LDS ----
    for (int idx = tid; idx < 2 * 196 * 8; idx += 128) {
        const int h   = idx / 1568;
        const int rem = idx - h * 1568;
        const int pos = rem >> 3;
        const int c   = rem & 7;
        const int ri  = pos / 14;
        const int rj  = pos - ri * 14;
        const float4* src = (const float4*)(vb +
            (base0 + (size_t)h * HWSZ + (R0 + ri) * WW + (C0 + rj)) * HD) + c;
        kv[h][c][pos] = *src;
    }

    // softmax in registers (overlaps V staging latency)
    float m = s[0];
    #pragma unroll
    for (int p = 1; p < 49; ++p) m = fmaxf(m, s[p]);
    float sum = 0.f;
    #pragma unroll
    for (int p = 0; p < 49; ++p) { s[p] = __expf(s[p] - m); sum += s[p]; }
    const float inv = 1.f / sum;

    __syncthreads();   // V staged

    float4 o[8];
    #pragma unroll
    for (int c = 0; c < 8; ++c) o[c] = make_float4(0.f, 0.f, 0.f, 0.f);
    #pragma unroll
    for (int pi = 0; pi < 7; ++pi) {
        #pragma unroll
        for (int pj = 0; pj < 7; ++pj) {
            const int pos = (ri0 + pi) * 14 + (rj0 + pj);
            const float wt = s[pi * 7 + pj];
            #pragma unroll
            for (int c = 0; c < 8; ++c) {
                const float4 vv = kv[h2][c][pos];
                o[c].x += wt * vv.x; o[c].y += wt * vv.y;
                o[c].z += wt * vv.z; o[c].w += wt * vv.w;
            }
        }
    }

    // write attention output in [B,H,W,NH*HD] layout for the proj GEMM
    float* optr = ob + ((size_t)b * HWSZ + qi * WW + qj) * CC + head * HD;
    #pragma unroll
    for (int c = 0; c < 8; ++c) {
        const float4 r = make_float4(o[c].x * inv, o[c].y * inv,
                                     o[c].z * inv, o[c].w * inv);
        ((float4*)optr)[c] = r;
    }
}

// ---------------- Kernel 3: output projection ----------------
// a [12544,128] @ w_proj[128,128] + b_proj -> out [12544,128]
__global__ __launch_bounds__(128) void proj_gemm(
    const float* __restrict__ a, const float* __restrict__ w,
    const float* __restrict__ bias, float* __restrict__ out)
{
    __shared__ float4 xs[1024];   // 32 x 128
    const int tid = threadIdx.x;
    const int m0 = blockIdx.x * 32;
    const float4* ag = (const float4*)(a + (size_t)m0 * CC);
    for (int idx = tid; idx < 1024; idx += 128) xs[idx] = ag[idx];
    __syncthreads();

    const int col = tid;
    float acc[32];
    const float bv = bias[col];
    #pragma unroll
    for (int r = 0; r < 32; ++r) acc[r] = bv;

    for (int kc = 0; kc < 32; ++kc) {
        const float w0 = w[(kc * 4 + 0) * CC + col];
        const float w1 = w[(kc * 4 + 1) * CC + col];
        const float w2 = w[(kc * 4 + 2) * CC + col];
        const float w3 = w[(kc * 4 + 3) * CC + col];
        #pragma unroll
        for (int r = 0; r < 32; ++r) {
            const float4 xv = xs[r * 32 + kc];
            acc[r] += xv.x * w0 + xv.y * w1 + xv.z * w2 + xv.w * w3;
        }
    }

    float* op = out + (size_t)m0 * CC + col;
    #pragma unroll
    for (int r = 0; r < 32; ++r) op[(size_t)r * CC] = acc[r];
}

extern "C" void kernel_launch(void* const* d_in, const int* in_sizes, int n_in,
                              void* d_out, int out_size, void* d_ws, size_t ws_size,
                              hipStream_t stream) {
    const float* x      = (const float*)d_in[0];
    const float* w_qkv  = (const float*)d_in[1];
    const float* b_qkv  = (const float*)d_in[2];
    const float* rpb    = (const float*)d_in[3];
    const float* w_proj = (const float*)d_in[4];
    const float* b_proj = (const float*)d_in[5];
    float* out = (float*)d_out;

    float* ws  = (float*)d_ws;
    float* qbf = ws;
    float* kbf = ws + QKV_ELE;
    float* vbf = ws + 2 * QKV_ELE;
    float* obf = ws + 3 * QKV_ELE;

    qkv_gemm<<<392, 384, 0, stream>>>(x, w_qkv, b_qkv, qbf, kbf, vbf);
    natten_attn<<<dim3(49, 2, BATCH), 128, 0, stream>>>(qbf, kbf, vbf, rpb, obf);
    proj_gemm<<<392, 128, 0, stream>>>(obf, w_proj, b_proj, out);
}

// Round 2
// 173.346 us; speedup vs baseline: 1.7382x; 1.7382x over previous
//
#include <hip/hip_runtime.h>

#define BATCH 4
#define HH 56
#define WW 56
#define CC 128
#define NHD 4
#define HD 32
#define KS 7
#define NB 3
#define HWSZ (HH * WW)        // 3136
#define RPBW 13
#define QKV_N 384
#define QKV_ELE ((size_t)BATCH * NHD * HWSZ * HD)   // 1,605,632 floats per tensor

// ---------------- Kernel 1: QKV GEMM (register-tiled) ----------------
// x [12544,128] @ w_qkv[128,384] -> q/k/v each [B,NH,HW,HD], q pre-scaled.
// 128x128 tile / block, 256 threads, 8x8 micro-tile per thread.
// Per kk: 4 ds_read_b128 -> 64 FMA (VALU-bound, not LDS-bound).
__global__ __launch_bounds__(256) void qkv_gemm(
    const float* __restrict__ x, const float* __restrict__ w,
    const float* __restrict__ bias,
    float* __restrict__ qb, float* __restrict__ kb, float* __restrict__ vb)
{
    __shared__ float As[32][132];   // [k][m], pad 132: write banks spread, 16B-aligned reads
    __shared__ float Bs[32][132];   // [k][n]

    const int tid = threadIdx.x;
    const int tx  = tid & 15;
    const int ty  = tid >> 4;
    const int m0  = blockIdx.x * 128;
    const int n0  = blockIdx.y * 128;

    float acc[8][8];
    {
        const float4 ba = *(const float4*)(bias + n0 + 4 * tx);
        const float4 bb = *(const float4*)(bias + n0 + 64 + 4 * tx);
        #pragma unroll
        for (int i = 0; i < 8; ++i) {
            acc[i][0] = ba.x; acc[i][1] = ba.y; acc[i][2] = ba.z; acc[i][3] = ba.w;
            acc[i][4] = bb.x; acc[i][5] = bb.y; acc[i][6] = bb.z; acc[i][7] = bb.w;
        }
    }

    for (int kc = 0; kc < 128; kc += 32) {
        // stage x tile transposed: As[k][m]
        #pragma unroll
        for (int t = tid; t < 1024; t += 256) {
            const int row = t >> 3;
            const int k4  = t & 7;
            const float4 xv = *(const float4*)(x + (size_t)(m0 + row) * CC + kc + 4 * k4);
            As[4 * k4 + 0][row] = xv.x;
            As[4 * k4 + 1][row] = xv.y;
            As[4 * k4 + 2][row] = xv.z;
            As[4 * k4 + 3][row] = xv.w;
        }
        // stage w tile: Bs[k][n]
        #pragma unroll
        for (int t = tid; t < 1024; t += 256) {
            const int kr = t >> 5;
            const int n4 = t & 31;
            *(float4*)&Bs[kr][4 * n4] =
                *(const float4*)(w + (size_t)(kc + kr) * QKV_N + n0 + 4 * n4);
        }
        __syncthreads();
        #pragma unroll
        for (int kk = 0; kk < 32; ++kk) {
            const float4 a0 = *(const float4*)&As[kk][4 * ty];
            const float4 a1 = *(const float4*)&As[kk][64 + 4 * ty];
            const float4 b0 = *(const float4*)&Bs[kk][4 * tx];
            const float4 b1 = *(const float4*)&Bs[kk][64 + 4 * tx];
            const float av[8] = {a0.x, a0.y, a0.z, a0.w, a1.x, a1.y, a1.z, a1.w};
            const float bv[8] = {b0.x, b0.y, b0.z, b0.w, b1.x, b1.y, b1.z, b1.w};
            #pragma unroll
            for (int i = 0; i < 8; ++i)
                #pragma unroll
                for (int j = 0; j < 8; ++j)
                    acc[i][j] += av[i] * bv[j];
        }
        __syncthreads();
    }

    // scatter into q/k/v [B,NH,HW,HD]; n-tile == tensor boundary so t uniform
    const int t     = n0 >> 7;   // 0=q 1=k 2=v
    float* dst      = (t == 0) ? qb : (t == 1) ? kb : vb;
    const float scl = (t == 0) ? 0.17677669529663687f : 1.0f;
    const int c0 = 4 * tx;            // local col group 0
    const int c1 = 64 + 4 * tx;       // local col group 1
    const int h0 = c0 >> 5, d0 = c0 & 31;
    const int h1 = c1 >> 5, d1 = c1 & 31;
    #pragma unroll
    for (int i = 0; i < 8; ++i) {
        const int m  = m0 + ((i >> 2) * 64) + 4 * ty + (i & 3);
        const int b  = m / HWSZ;
        const int ij = m - b * HWSZ;
        float* p0 = dst + ((size_t)(b * NHD + h0) * HWSZ + ij) * HD + d0;
        float* p1 = dst + ((size_t)(b * NHD + h1) * HWSZ + ij) * HD + d1;
        *(float4*)p0 = make_float4(acc[i][0] * scl, acc[i][1] * scl,
                                   acc[i][2] * scl, acc[i][3] * scl);
        *(float4*)p1 = make_float4(acc[i][4] * scl, acc[i][5] * scl,
                                   acc[i][6] * scl, acc[i][7] * scl);
    }
}

// ---------------- Kernel 2: neighborhood attention ----------------
// 1 wave / block: one (batch, head, 8x8 query tile). K and V halo both staged
// up-front (50 KB LDS); online softmax over the 7 window rows keeps the live
// set ~90 VGPRs (q32 + o32 + s7) -> no scratch spills.
__global__ __launch_bounds__(64) void natten_attn(
    const float* __restrict__ qb, const float* __restrict__ kb,
    const float* __restrict__ vb, const float* __restrict__ rpb,
    float* __restrict__ ob)
{
    __shared__ float4 Ks[8][196];   // [c][pos], 25088 B
    __shared__ float4 Vs[8][196];   // 25088 B

    const int lane = threadIdx.x;
    const int qi_l = lane >> 3;
    const int qj_l = lane & 7;
    const int ti = blockIdx.x / 7;
    const int tj = blockIdx.x % 7;
    const int head = blockIdx.y;
    const int b    = blockIdx.z;
    const int qi = ti * 8 + qi_l;
    const int qj = tj * 8 + qj_l;
    const int R0 = min(max(ti * 8 - NB, 0), HH - 14);
    const int C0 = min(max(tj * 8 - NB, 0), WW - 14);

    const size_t base = (size_t)(b * NHD + head) * HWSZ;

    // stage K halo (coalesced: 8 lanes cover one pixel's 128 B)
    for (int idx = lane; idx < 1568; idx += 64) {
        const int pos = idx >> 3;
        const int c   = idx & 7;
        const int ri  = pos / 14;
        const int rj  = pos - ri * 14;
        const size_t g = (base + (size_t)(R0 + ri) * WW + (C0 + rj)) * HD;
        Ks[c][pos] = ((const float4*)(kb + g))[c];
    }
    // stage V halo
    for (int idx = lane; idx < 1568; idx += 64) {
        const int pos = idx >> 3;
        const int c   = idx & 7;
        const int ri  = pos / 14;
        const int rj  = pos - ri * 14;
        const size_t g = (base + (size_t)(R0 + ri) * WW + (C0 + rj)) * HD;
        Vs[c][pos] = ((const float4*)(vb + g))[c];
    }

    // q fragment (pre-scaled in qkv_gemm)
    float4 qv[8];
    const float* qptr = qb + (base + (size_t)qi * WW + qj) * HD;
    #pragma unroll
    for (int c = 0; c < 8; ++c) qv[c] = ((const float4*)qptr)[c];

    const int si  = min(max(qi - NB, 0), HH - KS);
    const int sj  = min(max(qj - NB, 0), WW - KS);
    const int ri0 = si - R0;
    const int rj0 = sj - C0;
    const int oi  = si - qi + (KS - 1);
    const int oj  = sj - qj + (KS - 1);
    const float* rpbh = rpb + head * (RPBW * RPBW);

    __syncthreads();

    // online softmax over the 7 rows of the 7x7 window
    float m_s = -3.0e38f;
    float l   = 0.f;
    float4 o[8];
    #pragma unroll
    for (int c = 0; c < 8; ++c) o[c] = make_float4(0.f, 0.f, 0.f, 0.f);

    #pragma unroll
    for (int pi = 0; pi < 7; ++pi) {
        float s[7];
        #pragma unroll
        for (int pj = 0; pj < 7; ++pj) {
            const int pos = (ri0 + pi) * 14 + (rj0 + pj);
            float d = 0.f;
            #pragma unroll
            for (int c = 0; c < 8; ++c) {
                const float4 kk = Ks[c][pos];
                d += qv[c].x * kk.x + qv[c].y * kk.y + qv[c].z * kk.z + qv[c].w * kk.w;
            }
            s[pj] = d + rpbh[(oi + pi) * RPBW + (oj + pj)];
        }
        float rm = s[0];
        #pragma unroll
        for (int pj = 1; pj < 7; ++pj) rm = fmaxf(rm, s[pj]);
        const float nm    = fmaxf(m_s, rm);
        const float alpha = __expf(m_s - nm);
        float rl = 0.f;
        #pragma unroll
        for (int pj = 0; pj < 7; ++pj) { s[pj] = __expf(s[pj] - nm); rl += s[pj]; }
        l = l * alpha + rl;
        #pragma unroll
        for (int c = 0; c < 8; ++c) {
            o[c].x *= alpha; o[c].y *= alpha; o[c].z *= alpha; o[c].w *= alpha;
        }
        #pragma unroll
        for (int pj = 0; pj < 7; ++pj) {
            const int pos = (ri0 + pi) * 14 + (rj0 + pj);
            const float wt = s[pj];
            #pragma unroll
            for (int c = 0; c < 8; ++c) {
                const float4 vv = Vs[c][pos];
                o[c].x += wt * vv.x; o[c].y += wt * vv.y;
                o[c].z += wt * vv.z; o[c].w += wt * vv.w;
            }
        }
        m_s = nm;
    }

    const float inv = 1.f / l;
    float* optr = ob + ((size_t)b * HWSZ + (size_t)qi * WW + qj) * CC + head * HD;
    #pragma unroll
    for (int c = 0; c < 8; ++c) {
        ((float4*)optr)[c] = make_float4(o[c].x * inv, o[c].y * inv,
                                         o[c].z * inv, o[c].w * inv);
    }
}

// ---------------- Kernel 3: output projection (register-tiled) ----------------
// a [12544,128] @ w_proj[128,128] + b_proj. 64x128 tile / block, 256 threads,
// 4x8 micro-tile per thread.
__global__ __launch_bounds__(256) void proj_gemm(
    const float* __restrict__ a, const float* __restrict__ w,
    const float* __restrict__ bias, float* __restrict__ out)
{
    __shared__ float As[32][68];    // [k][m], 64 rows + pad
    __shared__ float Bs[32][132];   // [k][n]

    const int tid = threadIdx.x;
    const int tx  = tid & 15;
    const int ty  = tid >> 4;
    const int m0  = blockIdx.x * 64;

    float acc[4][8];
    {
        const float4 ba = *(const float4*)(bias + 4 * tx);
        const float4 bb = *(const float4*)(bias + 64 + 4 * tx);
        #pragma unroll
        for (int i = 0; i < 4; ++i) {
            acc[i][0] = ba.x; acc[i][1] = ba.y; acc[i][2] = ba.z; acc[i][3] = ba.w;
            acc[i][4] = bb.x; acc[i][5] = bb.y; acc[i][6] = bb.z; acc[i][7] = bb.w;
        }
    }

    for (int kc = 0; kc < 128; kc += 32) {
        #pragma unroll
        for (int t = tid; t < 512; t += 256) {
            const int row = t >> 3;
            const int k4  = t & 7;
            const float4 xv = *(const float4*)(a + (size_t)(m0 + row) * CC + kc + 4 * k4);
            As[4 * k4 + 0][row] = xv.x;
            As[4 * k4 + 1][row] = xv.y;
            As[4 * k4 + 2][row] = xv.z;
            As[4 * k4 + 3][row] = xv.w;
        }
        #pragma unroll
        for (int t = tid; t < 1024; t += 256) {
            const int kr = t >> 5;
            const int n4 = t & 31;
            *(float4*)&Bs[kr][4 * n4] =
                *(const float4*)(w + (size_t)(kc + kr) * CC + 4 * n4);
        }
        __syncthreads();
        #pragma unroll
        for (int kk = 0; kk < 32; ++kk) {
            const float4 a0 = *(const float4*)&As[kk][4 * ty];
            const float4 b0 = *(const float4*)&Bs[kk][4 * tx];
            const float4 b1 = *(const float4*)&Bs[kk][64 + 4 * tx];
            const float av[4] = {a0.x, a0.y, a0.z, a0.w};
            const float bv[8] = {b0.x, b0.y, b0.z, b0.w, b1.x, b1.y, b1.z, b1.w};
            #pragma unroll
            for (int i = 0; i < 4; ++i)
                #pragma unroll
                for (int j = 0; j < 8; ++j)
                    acc[i][j] += av[i] * bv[j];
        }
        __syncthreads();
    }

    #pragma unroll
    for (int i = 0; i < 4; ++i) {
        const int m = m0 + 4 * ty + i;
        float* p = out + (size_t)m * CC;
        *(float4*)(p + 4 * tx)      = make_float4(acc[i][0], acc[i][1], acc[i][2], acc[i][3]);
        *(float4*)(p + 64 + 4 * tx) = make_float4(acc[i][4], acc[i][5], acc[i][6], acc[i][7]);
    }
}

extern "C" void kernel_launch(void* const* d_in, const int* in_sizes, int n_in,
                              void* d_out, int out_size, void* d_ws, size_t ws_size,
                              hipStream_t stream) {
    const float* x      = (const float*)d_in[0];
    const float* w_qkv  = (const float*)d_in[1];
    const float* b_qkv  = (const float*)d_in[2];
    const float* rpb    = (const float*)d_in[3];
    const float* w_proj = (const float*)d_in[4];
    const float* b_proj = (const float*)d_in[5];
    float* out = (float*)d_out;

    float* ws  = (float*)d_ws;
    float* qbf = ws;
    float* kbf = ws + QKV_ELE;
    float* vbf = ws + 2 * QKV_ELE;
    float* obf = ws + 3 * QKV_ELE;

    qkv_gemm<<<dim3(98, 3), 256, 0, stream>>>(x, w_qkv, b_qkv, qbf, kbf, vbf);
    natten_attn<<<dim3(49, NHD, BATCH), 64, 0, stream>>>(qbf, kbf, vbf, rpb, obf);
    proj_gemm<<<196, 256, 0, stream>>>(obf, w_proj, b_proj, out);
}

// Round 3
// 127.473 us; speedup vs baseline: 2.3637x; 1.3599x over previous
//
#include <hip/hip_runtime.h>

#define BATCH 4
#define HH 56
#define WW 56
#define CC 128
#define NHD 4
#define HD 32
#define KS 7
#define NB 3
#define HWSZ (HH * WW)        // 3136
#define RPBW 13
#define QKV_N 384
#define QKV_ELE ((size_t)BATCH * NHD * HWSZ * HD)   // 1,605,632 floats per tensor

// ---------------- Kernel 1: QKV GEMM (register-tiled) ----------------
// x [12544,128] @ w_qkv[128,384] -> q/k/v each [B,NH,HW,HD], q pre-scaled.
// 64x128 tile / block (588 blocks ~ 2.3/CU), 256 threads, 4x8 micro-tile.
__global__ __launch_bounds__(256) void qkv_gemm(
    const float* __restrict__ x, const float* __restrict__ w,
    const float* __restrict__ bias,
    float* __restrict__ qb, float* __restrict__ kb, float* __restrict__ vb)
{
    __shared__ float As[32][68];    // [k][m], 64 rows + pad
    __shared__ float Bs[32][132];   // [k][n]

    const int tid = threadIdx.x;
    const int tx  = tid & 15;
    const int ty  = tid >> 4;       // 0..15 -> rows 4ty..4ty+3
    const int m0  = blockIdx.x * 64;
    const int n0  = blockIdx.y * 128;

    float acc[4][8];
    {
        const float4 ba = *(const float4*)(bias + n0 + 4 * tx);
        const float4 bb = *(const float4*)(bias + n0 + 64 + 4 * tx);
        #pragma unroll
        for (int i = 0; i < 4; ++i) {
            acc[i][0] = ba.x; acc[i][1] = ba.y; acc[i][2] = ba.z; acc[i][3] = ba.w;
            acc[i][4] = bb.x; acc[i][5] = bb.y; acc[i][6] = bb.z; acc[i][7] = bb.w;
        }
    }

    for (int kc = 0; kc < 128; kc += 32) {
        // stage x tile transposed: As[k][m]   (64 rows x 8 k-groups = 512 tasks)
        #pragma unroll
        for (int t = tid; t < 512; t += 256) {
            const int row = t >> 3;
            const int k4  = t & 7;
            const float4 xv = *(const float4*)(x + (size_t)(m0 + row) * CC + kc + 4 * k4);
            As[4 * k4 + 0][row] = xv.x;
            As[4 * k4 + 1][row] = xv.y;
            As[4 * k4 + 2][row] = xv.z;
            As[4 * k4 + 3][row] = xv.w;
        }
        // stage w tile: Bs[k][n]  (32 k x 32 n-groups = 1024 tasks)
        #pragma unroll
        for (int t = tid; t < 1024; t += 256) {
            const int kr = t >> 5;
            const int n4 = t & 31;
            *(float4*)&Bs[kr][4 * n4] =
                *(const float4*)(w + (size_t)(kc + kr) * QKV_N + n0 + 4 * n4);
        }
        __syncthreads();
        #pragma unroll
        for (int kk = 0; kk < 32; ++kk) {
            const float4 a0 = *(const float4*)&As[kk][4 * ty];
            const float4 b0 = *(const float4*)&Bs[kk][4 * tx];
            const float4 b1 = *(const float4*)&Bs[kk][64 + 4 * tx];
            const float av[4] = {a0.x, a0.y, a0.z, a0.w};
            const float bv[8] = {b0.x, b0.y, b0.z, b0.w, b1.x, b1.y, b1.z, b1.w};
            #pragma unroll
            for (int i = 0; i < 4; ++i)
                #pragma unroll
                for (int j = 0; j < 8; ++j)
                    acc[i][j] += av[i] * bv[j];
        }
        __syncthreads();
    }

    // scatter into q/k/v [B,NH,HW,HD]; n-tile == tensor boundary so t uniform
    const int t     = n0 >> 7;   // 0=q 1=k 2=v
    float* dst      = (t == 0) ? qb : (t == 1) ? kb : vb;
    const float scl = (t == 0) ? 0.17677669529663687f : 1.0f;
    const int c0 = 4 * tx;
    const int c1 = 64 + 4 * tx;
    const int h0 = c0 >> 5, d0 = c0 & 31;
    const int h1 = c1 >> 5, d1 = c1 & 31;
    const int b  = m0 / HWSZ;        // 64 | 3136 so tile never crosses b
    #pragma unroll
    for (int i = 0; i < 4; ++i) {
        const int m  = m0 + 4 * ty + i;
        const int ij = m - b * HWSZ;
        float* p0 = dst + ((size_t)(b * NHD + h0) * HWSZ + ij) * HD + d0;
        float* p1 = dst + ((size_t)(b * NHD + h1) * HWSZ + ij) * HD + d1;
        *(float4*)p0 = make_float4(acc[i][0] * scl, acc[i][1] * scl,
                                   acc[i][2] * scl, acc[i][3] * scl);
        *(float4*)p1 = make_float4(acc[i][4] * scl, acc[i][5] * scl,
                                   acc[i][6] * scl, acc[i][7] * scl);
    }
}

// ---------------- Kernel 2: neighborhood attention ----------------
// Block = 256 threads = 4 waves per (b, head, 8x8 query tile).
// Each query is handled by a quad: lane sub=tid&3 owns 8 channels.
// QK partial dots reduced across the quad with DPP shuffles (VALU-rate).
// K+V halo staged once in LDS (pos-dim padded to 197 -> subs on distinct banks).
__global__ __launch_bounds__(256) void natten_attn(
    const float* __restrict__ qb, const float* __restrict__ kb,
    const float* __restrict__ vb, const float* __restrict__ rpb,
    float* __restrict__ ob)
{
    __shared__ float4 Ks[8][197];   // [c][pos]
    __shared__ float4 Vs[8][197];
    __shared__ float rpbs[RPBW * RPBW];

    const int tid = threadIdx.x;
    const int qid = tid >> 2;       // 0..63 query within 8x8 tile
    const int sub = tid & 3;        // channel-quarter
    const int qi_l = qid >> 3;
    const int qj_l = qid & 7;
    const int ti = blockIdx.x / 7;
    const int tj = blockIdx.x % 7;
    const int head = blockIdx.y;
    const int b    = blockIdx.z;
    const int qi = ti * 8 + qi_l;
    const int qj = tj * 8 + qj_l;
    const int R0 = min(max(ti * 8 - NB, 0), HH - 14);
    const int C0 = min(max(tj * 8 - NB, 0), WW - 14);

    const size_t base = (size_t)(b * NHD + head) * HWSZ;

    if (tid < RPBW * RPBW) rpbs[tid] = rpb[head * (RPBW * RPBW) + tid];

    // stage K+V halo (8 lanes cover one pixel's 128 B -> coalesced)
    for (int idx = tid; idx < 1568; idx += 256) {
        const int pos = idx >> 3;
        const int c   = idx & 7;
        const int ri  = pos / 14;
        const int rj  = pos - ri * 14;
        const size_t g = (base + (size_t)(R0 + ri) * WW + (C0 + rj)) * HD;
        Ks[c][pos] = ((const float4*)(kb + g))[c];
        Vs[c][pos] = ((const float4*)(vb + g))[c];
    }

    // q fragment: my 8 channels (pre-scaled in qkv_gemm)
    const int c0 = sub * 2;
    const float4* qp = (const float4*)(qb + (base + (size_t)qi * WW + qj) * HD) + c0;
    const float4 q0 = qp[0];
    const float4 q1 = qp[1];

    const int si  = min(max(qi - NB, 0), HH - KS);
    const int sj  = min(max(qj - NB, 0), WW - KS);
    const int ri0 = si - R0;
    const int rj0 = sj - C0;
    const int oi  = si - qi + (KS - 1);
    const int oj  = sj - qj + (KS - 1);

    __syncthreads();

    // scores: partial dot over my 8 channels, quad-reduce via DPP shuffles
    float s[49];
    #pragma unroll
    for (int pi = 0; pi < 7; ++pi) {
        const int rowoff = (ri0 + pi) * 14 + rj0;
        const int boff   = (oi + pi) * RPBW + oj;
        #pragma unroll
        for (int pj = 0; pj < 7; ++pj) {
            const int pos = rowoff + pj;
            const float4 k0 = Ks[c0][pos];
            const float4 k1 = Ks[c0 + 1][pos];
            float d = q0.x * k0.x + q0.y * k0.y + q0.z * k0.z + q0.w * k0.w
                    + q1.x * k1.x + q1.y * k1.y + q1.z * k1.z + q1.w * k1.w;
            d += __shfl_xor(d, 1, 64);
            d += __shfl_xor(d, 2, 64);
            s[pi * 7 + pj] = d + rpbs[boff + pj];
        }
    }

    // softmax (replicated across the quad -- no communication needed)
    float m = s[0];
    #pragma unroll
    for (int p = 1; p < 49; ++p) m = fmaxf(m, s[p]);
    float l = 0.f;
    #pragma unroll
    for (int p = 0; p < 49; ++p) { s[p] = __expf(s[p] - m); l += s[p]; }
    const float inv = 1.f / l;

    // PV over my 8 channels
    float4 o0 = make_float4(0.f, 0.f, 0.f, 0.f);
    float4 o1 = make_float4(0.f, 0.f, 0.f, 0.f);
    #pragma unroll
    for (int pi = 0; pi < 7; ++pi) {
        const int rowoff = (ri0 + pi) * 14 + rj0;
        #pragma unroll
        for (int pj = 0; pj < 7; ++pj) {
            const int pos = rowoff + pj;
            const float wt = s[pi * 7 + pj];
            const float4 v0 = Vs[c0][pos];
            const float4 v1 = Vs[c0 + 1][pos];
            o0.x += wt * v0.x; o0.y += wt * v0.y; o0.z += wt * v0.z; o0.w += wt * v0.w;
            o1.x += wt * v1.x; o1.y += wt * v1.y; o1.z += wt * v1.z; o1.w += wt * v1.w;
        }
    }

    // write [B,H,W,NH*HD] for the proj GEMM; quad writes one 128 B pixel slice
    float* op = ob + ((size_t)b * HWSZ + (size_t)qi * WW + qj) * CC + head * HD + sub * 8;
    ((float4*)op)[0] = make_float4(o0.x * inv, o0.y * inv, o0.z * inv, o0.w * inv);
    ((float4*)op)[1] = make_float4(o1.x * inv, o1.y * inv, o1.z * inv, o1.w * inv);
}

// ---------------- Kernel 3: output projection (register-tiled) ----------------
// a [12544,128] @ w_proj[128,128] + b_proj. 32x128 tile (392 blocks), 256 thr,
// 2x8 micro-tile per thread.
__global__ __launch_bounds__(256) void proj_gemm(
    const float* __restrict__ a, const float* __restrict__ w,
    const float* __restrict__ bias, float* __restrict__ out)
{
    __shared__ float As[32][36];    // [k][m], 32 rows + pad
    __shared__ float Bs[32][132];   // [k][n]

    const int tid = threadIdx.x;
    const int tx  = tid & 15;
    const int ty  = tid >> 4;       // 0..15 -> rows 2ty, 2ty+1
    const int m0  = blockIdx.x * 32;

    float acc[2][8];
    {
        const float4 ba = *(const float4*)(bias + 4 * tx);
        const float4 bb = *(const float4*)(bias + 64 + 4 * tx);
        #pragma unroll
        for (int i = 0; i < 2; ++i) {
            acc[i][0] = ba.x; acc[i][1] = ba.y; acc[i][2] = ba.z; acc[i][3] = ba.w;
            acc[i][4] = bb.x; acc[i][5] = bb.y; acc[i][6] = bb.z; acc[i][7] = bb.w;
        }
    }

    for (int kc = 0; kc < 128; kc += 32) {
        {   // stage a tile transposed: 32 rows x 8 k-groups = 256 tasks (1/thread)
            const int row = tid >> 3;
            const int k4  = tid & 7;
            const float4 xv = *(const float4*)(a + (size_t)(m0 + row) * CC + kc + 4 * k4);
            As[4 * k4 + 0][row] = xv.x;
            As[4 * k4 + 1][row] = xv.y;
            As[4 * k4 + 2][row] = xv.z;
            As[4 * k4 + 3][row] = xv.w;
        }
        #pragma unroll
        for (int t = tid; t < 1024; t += 256) {
            const int kr = t >> 5;
            const int n4 = t & 31;
            *(float4*)&Bs[kr][4 * n4] =
                *(const float4*)(w + (size_t)(kc + kr) * CC + 4 * n4);
        }
        __syncthreads();
        #pragma unroll
        for (int kk = 0; kk < 32; ++kk) {
            const float2 a0 = *(const float2*)&As[kk][2 * ty];
            const float4 b0 = *(const float4*)&Bs[kk][4 * tx];
            const float4 b1 = *(const float4*)&Bs[kk][64 + 4 * tx];
            const float av[2] = {a0.x, a0.y};
            const float bv[8] = {b0.x, b0.y, b0.z, b0.w, b1.x, b1.y, b1.z, b1.w};
            #pragma unroll
            for (int i = 0; i < 2; ++i)
                #pragma unroll
                for (int j = 0; j < 8; ++j)
                    acc[i][j] += av[i] * bv[j];
        }
        __syncthreads();
    }

    #pragma unroll
    for (int i = 0; i < 2; ++i) {
        const int m = m0 + 2 * ty + i;
        float* p = out + (size_t)m * CC;
        *(float4*)(p + 4 * tx)      = make_float4(acc[i][0], acc[i][1], acc[i][2], acc[i][3]);
        *(float4*)(p + 64 + 4 * tx) = make_float4(acc[i][4], acc[i][5], acc[i][6], acc[i][7]);
    }
}

extern "C" void kernel_launch(void* const* d_in, const int* in_sizes, int n_in,
                              void* d_out, int out_size, void* d_ws, size_t ws_size,
                              hipStream_t stream) {
    const float* x      = (const float*)d_in[0];
    const float* w_qkv  = (const float*)d_in[1];
    const float* b_qkv  = (const float*)d_in[2];
    const float* rpb    = (const float*)d_in[3];
    const float* w_proj = (const float*)d_in[4];
    const float* b_proj = (const float*)d_in[5];
    float* out = (float*)d_out;

    float* ws  = (float*)d_ws;
    float* qbf = ws;
    float* kbf = ws + QKV_ELE;
    float* vbf = ws + 2 * QKV_ELE;
    float* obf = ws + 3 * QKV_ELE;

    qkv_gemm<<<dim3(196, 3), 256, 0, stream>>>(x, w_qkv, b_qkv, qbf, kbf, vbf);
    natten_attn<<<dim3(49, NHD, BATCH), 256, 0, stream>>>(qbf, kbf, vbf, rpb, obf);
    proj_gemm<<<392, 256, 0, stream>>>(obf, w_proj, b_proj, out);
}